// Round 1
// baseline (445.491 us; speedup 1.0000x reference)
//
#include <hip/hip_runtime.h>
#include <cstdint>

// SpacetimeNonLocalBlock: B=4, C=256, T*H*W=N=6272, IC=128.
// R8: flash6 = flash5 with register-staged K/V prefetch replaced by
// global_load_lds (width 16) with pre-swizzled per-lane SOURCE addresses
// (LDS dest linear, per guide): frees stgK/stgV (16 VGPRs) + all ds_writes.
// V LDS layout changed padded [128][36] -> xor-swizzled [128][32] so every PV
// operand is one aligned ds_read_b128. Total regs (V+A) targeted <=128 via
// __launch_bounds__(256,4): occupancy 2 -> 4 waves/SIMD (the kernel was
// latency-bound: per-SIMD VALU ~11%, MFMA ~5%). fmax reduce -> 4-deep tree.

#define BB   4
#define CCH  256
#define NPOS 6272
#define ICH  128
#define BNIC ((size_t)BB * NPOS * ICH)
#define KSPL 4
#define KLEN (NPOS / KSPL)   // 1568
#define TKF  32
#define NITK (KLEN / TKF)    // 49
#define SLACK 12.0f

typedef __attribute__((ext_vector_type(8)))  _Float16 h8v;  // 8 f16 MFMA frag
typedef __attribute__((ext_vector_type(16))) float fx16;    // 32x32 acc

__device__ __forceinline__ unsigned short f2h(float f) {
  _Float16 h = (_Float16)f;
  return __builtin_bit_cast(unsigned short, h);
}
__device__ __forceinline__ unsigned int pkh(float lo, float hi) {
  return __builtin_bit_cast(unsigned int, __builtin_amdgcn_cvt_pkrtz(lo, hi));
}

// ---------------------------------------------------------------------------
// proj_qkv: fused Q/K/V projections. grid (N/64, B); block 256.
// Q,K -> [b][n][128] f16 (Q pre-scaled log2e); V -> V^T [b][128][N] f16.
// LDS 30.5 KB: Xt[16][68] + Wt[6][16][68]. Inner: 1 av + 6 bv b128 per kk.
// ---------------------------------------------------------------------------
__global__ __launch_bounds__(256, 1)
void proj_qkv(const float* __restrict__ x,
              const float* __restrict__ Wtheta,
              const float* __restrict__ Wphi,
              const float* __restrict__ Wg,
              unsigned short* __restrict__ Qg,
              unsigned short* __restrict__ Kg,
              unsigned short* __restrict__ Vtg) {
  const int n0 = blockIdx.x * 64;
  const int b  = blockIdx.y;
  __shared__ float Xt[16][68];      // [k][n]
  __shared__ float Wt[6][16][68];   // [tile][k][o]
  const int tid = threadIdx.x;
  const int tx = tid & 15, ty = tid >> 4;
  float acc[6][4][4] = {};          // [tile][n_i][o_j]
  const float* Ws[3] = {Wtheta, Wphi, Wg};

  for (int c0 = 0; c0 < CCH; c0 += 16) {
    {
      const int nn = tid & 63, k4 = tid >> 6;
      #pragma unroll
      for (int q = 0; q < 4; ++q) {
        const int kk = k4 + q * 4;
        Xt[kk][nn] = x[((size_t)(b * CCH + c0 + kk)) * NPOS + n0 + nn];
      }
      const int wk = tid & 15, wo = tid >> 4;
      #pragma unroll
      for (int w = 0; w < 6; ++w) {
        const float* W = Ws[w >> 1];
        const int o_half = (w & 1) * 64;
        #pragma unroll
        for (int q = 0; q < 4; ++q) {
          const int oo = wo + q * 16;
          Wt[w][wk][oo] = W[(size_t)(o_half + oo) * CCH + c0 + wk];
        }
      }
    }
    __syncthreads();
    #pragma unroll
    for (int kk = 0; kk < 16; ++kk) {
      const float4 av = *(const float4*)&Xt[kk][ty * 4];
      const float a_[4] = {av.x, av.y, av.z, av.w};
      #pragma unroll
      for (int w = 0; w < 6; ++w) {
        const float4 bv = *(const float4*)&Wt[w][kk][tx * 4];
        const float b_[4] = {bv.x, bv.y, bv.z, bv.w};
        #pragma unroll
        for (int i = 0; i < 4; ++i)
          #pragma unroll
          for (int j = 0; j < 4; ++j) acc[w][i][j] += a_[i] * b_[j];
      }
    }
    __syncthreads();
  }

  const float LOG2E = 1.4426950408889634f;
  // Q (tiles 0,1) and K (tiles 2,3): [n][o] rows
  #pragma unroll
  for (int w = 0; w < 4; ++w) {
    const int o_half = (w & 1) * 64;
    unsigned short* Out = (w < 2) ? Qg : Kg;
    const float scl = (w < 2) ? LOG2E : 1.0f;
    #pragma unroll
    for (int i = 0; i < 4; ++i) {
      ushort4 v;
      v.x = f2h(acc[w][i][0] * scl); v.y = f2h(acc[w][i][1] * scl);
      v.z = f2h(acc[w][i][2] * scl); v.w = f2h(acc[w][i][3] * scl);
      *(ushort4*)&Out[((size_t)b * NPOS + n0 + ty * 4 + i) * ICH + o_half + tx * 4] = v;
    }
  }
  // V (tiles 4,5): V^T[o][n] — transpose in-register (i<->j roles)
  #pragma unroll
  for (int w = 4; w < 6; ++w) {
    const int o_half = (w & 1) * 64;
    #pragma unroll
    for (int j = 0; j < 4; ++j) {
      const int o = o_half + tx * 4 + j;
      ushort4 v;
      v.x = f2h(acc[w][0][j]); v.y = f2h(acc[w][1][j]);
      v.z = f2h(acc[w][2][j]); v.w = f2h(acc[w][3][j]);
      *(ushort4*)&Vtg[((size_t)b * ICH + o) * NPOS + n0 + ty * 4] = v;
    }
  }
}

// ---------------------------------------------------------------------------
// flash6: grid (49, KSPL, B), 4 waves, q=32/wave, TK=32. Slack-fold softmax.
// LDS 32 KB: Ks[2][32x128] 16B-slot xor-swz, Vs[2][128x32] 16B-slot xor-swz.
// K/V staging via global_load_lds w=16, source pre-swizzled per-lane.
// ---------------------------------------------------------------------------
__global__ __launch_bounds__(256, 4)
void flash6(const unsigned short* __restrict__ Qg,
            const unsigned short* __restrict__ Kg,
            const unsigned short* __restrict__ Vtg,
            unsigned short* __restrict__ Opart,
            float* __restrict__ Mpart,
            float* __restrict__ Lpart) {
  __shared__ unsigned short Ks[2][TKF * 128];   // 8 KB per buf
  __shared__ unsigned short Vs[2][128 * 32];    // 8 KB per buf

  const int b   = blockIdx.z;
  const int spl = blockIdx.y;
  const int n0  = blockIdx.x * 128;
  const int kb  = spl * KLEN;
  const int tid = threadIdx.x;
  const int lane = tid & 63, wv = tid >> 6;
  const int qlane = lane & 31, g = lane >> 5;
  const int swz = qlane & 15;

  h8v qf[8];
  {
    const size_t qbase = ((size_t)b * NPOS + n0 + 32 * wv + qlane) * ICH;
    #pragma unroll
    for (int cs = 0; cs < 8; ++cs)
      qf[cs] = *(const h8v*)&Qg[qbase + cs * 16 + g * 8];
  }

  // Per-lane 32-bit source offsets for global_load_lds staging.
  // Wave wv, inst i covers LDS ushorts [(wv*2+i)*512, +512) of each tile;
  // lane's 16B goes to linear LDS off -> invert the read swizzle on the src.
  unsigned kOff[2], vOff[2];
  #pragma unroll
  for (int i = 0; i < 2; ++i) {
    const unsigned uoff = (unsigned)(wv * 2 + i) * 512 + (unsigned)lane * 8;
    const unsigned krow = uoff >> 7, kslot = (uoff >> 3) & 15;
    const unsigned kgc  = kslot ^ (krow & 15);
    kOff[i] = (unsigned)(b * NPOS + kb + krow) * ICH + kgc * 8;
    const unsigned vrow = uoff >> 5, vslot = (uoff >> 3) & 3;
    const unsigned vgc  = vslot ^ (vrow & 3);
    vOff[i] = (unsigned)(b * ICH + vrow) * NPOS + kb + vgc * 8;
  }

  auto STAGE = [&](int bufi) {
    #pragma unroll
    for (int i = 0; i < 2; ++i) {
      __builtin_amdgcn_global_load_lds(
          (const __attribute__((address_space(1))) void*)&Kg[kOff[i]],
          (__attribute__((address_space(3))) void*)&Ks[bufi][(wv * 2 + i) * 512],
          16, 0, 0);
      __builtin_amdgcn_global_load_lds(
          (const __attribute__((address_space(1))) void*)&Vtg[vOff[i]],
          (__attribute__((address_space(3))) void*)&Vs[bufi][(wv * 2 + i) * 512],
          16, 0, 0);
      kOff[i] += TKF * ICH;
      vOff[i] += TKF;
    }
  };

  STAGE(0);
  __syncthreads();

  float m_run = -1e30f, m_true = -1e30f, l_run = 0.0f;
  fx16 accO[4];
  #pragma unroll
  for (int mt = 0; mt < 4; ++mt) accO[mt] = (fx16)(0.0f);

  for (int it = 0; it < NITK; ++it) {
    const int cur = it & 1;
    if (it + 1 < NITK) STAGE(cur ^ 1);   // prefetch overlaps this tile's compute

    // ---- S^T = K . Q^T ----
    fx16 accS = (fx16)(0.0f);
    #pragma unroll
    for (int cs = 0; cs < 8; ++cs) {
      const h8v aK = *(const h8v*)&Ks[cur][qlane * 128 + ((2 * cs + g) ^ swz) * 8];
      accS = __builtin_amdgcn_mfma_f32_32x32x16_f16(aK, qf[cs], accS, 0, 0, 0);
    }

    // ---- slack-fold online softmax (log2 domain), tree max ----
    float a0 = fmaxf(accS[0], accS[1]),   a1 = fmaxf(accS[2], accS[3]);
    float a2 = fmaxf(accS[4], accS[5]),   a3 = fmaxf(accS[6], accS[7]);
    float a4 = fmaxf(accS[8], accS[9]),   a5 = fmaxf(accS[10], accS[11]);
    float a6 = fmaxf(accS[12], accS[13]), a7 = fmaxf(accS[14], accS[15]);
    a0 = fmaxf(a0, a1); a2 = fmaxf(a2, a3); a4 = fmaxf(a4, a5); a6 = fmaxf(a6, a7);
    float mx = fmaxf(fmaxf(a0, a2), fmaxf(a4, a6));
    mx = fmaxf(mx, __shfl_xor(mx, 32));
    m_true = fmaxf(m_true, mx);
    const bool fold = __any(mx > m_run + SLACK);
    const float mn = fold ? fmaxf(m_run, mx) : m_run;
    float lsum = 0.0f;
    unsigned int pk[4][2];
    #pragma unroll
    for (int u = 0; u < 4; ++u) {
      const float p0 = exp2f(accS[4 * u + 0] - mn);
      const float p1 = exp2f(accS[4 * u + 1] - mn);
      const float p2 = exp2f(accS[4 * u + 2] - mn);
      const float p3 = exp2f(accS[4 * u + 3] - mn);
      lsum += (p0 + p1) + (p2 + p3);
      pk[u][0] = pkh(p0, p1);
      pk[u][1] = pkh(p2, p3);
    }
    lsum += __shfl_xor(lsum, 32);
    if (fold) {
      const float alpha = exp2f(m_run - mn);
      l_run = l_run * alpha + lsum;
      m_run = mn;
      #pragma unroll
      for (int mt = 0; mt < 4; ++mt)
        #pragma unroll
        for (int r = 0; r < 16; ++r) accO[mt][r] *= alpha;
    } else {
      l_run += lsum;
    }

    // ---- PV: O^T += V^T . P^T ----
    #pragma unroll
    for (int s = 0; s < 2; ++s) {
      const unsigned int s0 = pk[2 * s + (g ^ 1)][0];
      const unsigned int s1 = pk[2 * s + (g ^ 1)][1];
      const unsigned int t0 = __shfl_xor(s0, 32);
      const unsigned int t1 = __shfl_xor(s1, 32);
      union { unsigned int u[4]; h8v v; } bP;
      bP.u[0] = g ? t0 : pk[2 * s][0];
      bP.u[1] = g ? t1 : pk[2 * s][1];
      bP.u[2] = g ? pk[2 * s + 1][0] : t0;
      bP.u[3] = g ? pk[2 * s + 1][1] : t1;
      const int vbase = qlane * 32 + (((2 * s + g) ^ (qlane & 3)) * 8);
      #pragma unroll
      for (int mt = 0; mt < 4; ++mt) {
        const h8v aV = *(const h8v*)&Vs[cur][mt * 1024 + vbase];
        accO[mt] = __builtin_amdgcn_mfma_f32_32x32x16_f16(aV, bP.v, accO[mt], 0, 0, 0);
      }
    }

    __syncthreads();   // drains prefetch (vmcnt) + finishes reads of cur
  }

  // epilogue: renormalize to true max, store f16 partial O + (m,l)
  const float scale = exp2f(m_run - m_true);
  const int ncol = n0 + 32 * wv + qlane;
  const size_t obase = (size_t)(b * KSPL + spl) * ICH * NPOS;
  #pragma unroll
  for (int mt = 0; mt < 4; ++mt)
    #pragma unroll
    for (int r = 0; r < 16; ++r) {
      const int d = 32 * mt + (r & 3) + 8 * (r >> 2) + 4 * g;
      Opart[obase + (size_t)d * NPOS + ncol] = f2h(accO[mt][r] * scale);
    }
  if (g == 0) {
    Mpart[(size_t)(b * KSPL + spl) * NPOS + ncol] = m_true;
    Lpart[(size_t)(b * KSPL + spl) * NPOS + ncol] = l_run * scale;
  }
}

// ---------------------------------------------------------------------------
// merge (2n per thread): Y^T[b][d][n] = sum_s 2^{m_s-M} O_s / sum_s 2^{m_s-M} l_s
// ---------------------------------------------------------------------------
__global__ __launch_bounds__(256, 2)
void merge_kernel(const unsigned short* __restrict__ Opart,
                  const float* __restrict__ Mpart,
                  const float* __restrict__ Lpart,
                  float* __restrict__ Yt) {
  const int idx = (blockIdx.x * 256 + threadIdx.x) * 2;   // 0 .. B*N-1 step 2
  const int b = idx / NPOS, n = idx % NPOS;
  float m[KSPL][2], l[KSPL][2], M0 = -1e30f, M1 = -1e30f;
  #pragma unroll
  for (int s = 0; s < KSPL; ++s) {
    const size_t base = (size_t)(b * KSPL + s) * NPOS + n;
    m[s][0] = Mpart[base]; m[s][1] = Mpart[base + 1];
    l[s][0] = Lpart[base]; l[s][1] = Lpart[base + 1];
    M0 = fmaxf(M0, m[s][0]); M1 = fmaxf(M1, m[s][1]);
  }
  float w[KSPL][2], lt0 = 0.0f, lt1 = 0.0f;
  #pragma unroll
  for (int s = 0; s < KSPL; ++s) {
    w[s][0] = exp2f(m[s][0] - M0); lt0 += w[s][0] * l[s][0];
    w[s][1] = exp2f(m[s][1] - M1); lt1 += w[s][1] * l[s][1];
  }
  const float inv0 = 1.0f / lt0, inv1 = 1.0f / lt1;
  for (int d = 0; d < ICH; ++d) {
    float a0 = 0.0f, a1 = 0.0f;
    #pragma unroll
    for (int s = 0; s < KSPL; ++s) {
      const unsigned int u = *(const unsigned int*)
        &Opart[((size_t)(b * KSPL + s) * ICH + d) * NPOS + n];
      a0 += w[s][0] * (float)__builtin_bit_cast(_Float16, (unsigned short)(u & 0xffff));
      a1 += w[s][1] * (float)__builtin_bit_cast(_Float16, (unsigned short)(u >> 16));
    }
    float2 o; o.x = a0 * inv0; o.y = a1 * inv1;
    *(float2*)&Yt[((size_t)b * ICH + d) * NPOS + n] = o;
  }
}

// ---------------------------------------------------------------------------
// zres: out[b][c][n] = sum_ic Wz[c][ic]*Y^T[b][ic][n] + x. 128x128 block,
// 8x8 thread tile via wave quadrants (both LDS operand reads <=2-way).
// ---------------------------------------------------------------------------
__global__ __launch_bounds__(256, 2)
void zres_kernel(const float* __restrict__ x,
                 const float* __restrict__ Wz,
                 const float* __restrict__ Yt,
                 float* __restrict__ out) {
  const int n0 = blockIdx.x * 128;
  const int c0 = blockIdx.y * 128;
  const int b  = blockIdx.z;
  __shared__ float Yts[16][128];   // [k(ic)][n]
  __shared__ float Wzt[16][128];   // [k][c]
  const int tid = threadIdx.x;
  const int lane = tid & 63, wv = tid >> 6;
  const int tn = lane & 7, tc = lane >> 3;           // 8x8 within wave
  const int nb = (wv & 1) * 64 + tn * 8;             // n offset in block
  const int cb = (wv >> 1) * 64 + tc * 8;            // c offset in block
  float acc[8][8] = {};                              // [c_i][n_j]

  for (int ic0 = 0; ic0 < ICH; ic0 += 16) {
    {
      const int nn = tid & 127, kh = tid >> 7;
      #pragma unroll
      for (int q = 0; q < 8; ++q) {
        const int kk = kh + q * 2;
        Yts[kk][nn] = Yt[((size_t)b * ICH + ic0 + kk) * NPOS + n0 + nn];
      }
      const int wk = tid & 15, wo = tid >> 4;
      #pragma unroll
      for (int q = 0; q < 8; ++q) {
        const int cc = wo + q * 16;
        Wzt[wk][cc] = Wz[(size_t)(c0 + cc) * ICH + ic0 + wk];
      }
    }
    __syncthreads();
    #pragma unroll
    for (int kk = 0; kk < 16; ++kk) {
      const float4 a0 = *(const float4*)&Wzt[kk][cb];
      const float4 a1 = *(const float4*)&Wzt[kk][cb + 4];
      const float4 b0 = *(const float4*)&Yts[kk][nb];
      const float4 b1 = *(const float4*)&Yts[kk][nb + 4];
      const float a_[8] = {a0.x, a0.y, a0.z, a0.w, a1.x, a1.y, a1.z, a1.w};
      const float b_[8] = {b0.x, b0.y, b0.z, b0.w, b1.x, b1.y, b1.z, b1.w};
      #pragma unroll
      for (int i = 0; i < 8; ++i)
        #pragma unroll
        for (int j = 0; j < 8; ++j) acc[i][j] += a_[i] * b_[j];
    }
    __syncthreads();
  }
  #pragma unroll
  for (int i = 0; i < 8; ++i) {
    const size_t base = ((size_t)(b * CCH + c0 + cb + i)) * NPOS + n0 + nb;
    const float4 x0 = *(const float4*)&x[base];
    const float4 x1 = *(const float4*)&x[base + 4];
    float4 v0, v1;
    v0.x = acc[i][0] + x0.x; v0.y = acc[i][1] + x0.y;
    v0.z = acc[i][2] + x0.z; v0.w = acc[i][3] + x0.w;
    v1.x = acc[i][4] + x1.x; v1.y = acc[i][5] + x1.y;
    v1.z = acc[i][6] + x1.z; v1.w = acc[i][7] + x1.w;
    *(float4*)&out[base]     = v0;
    *(float4*)&out[base + 4] = v1;
  }
}

// ---------------------------------------------------------------------------
extern "C" void kernel_launch(void* const* d_in, const int* in_sizes, int n_in,
                              void* d_out, int out_size, void* d_ws, size_t ws_size,
                              hipStream_t stream) {
  const float* x      = (const float*)d_in[0];
  const float* Wg     = (const float*)d_in[1];
  const float* Wtheta = (const float*)d_in[2];
  const float* Wphi   = (const float*)d_in[3];
  const float* Wz     = (const float*)d_in[4];
  float* out = (float*)d_out;

  unsigned short* Qg    = (unsigned short*)d_ws;
  unsigned short* Kg    = Qg + BNIC;
  unsigned short* Vtg   = Kg + BNIC;
  unsigned short* Opart = Vtg + BNIC;                    // KSPL*BNIC ushorts
  float* Mpart = (float*)(Opart + (size_t)KSPL * BNIC);  // KSPL*B*N floats
  float* Lpart = Mpart + (size_t)KSPL * BB * NPOS;       // KSPL*B*N floats
  float* Yt    = (float*)Qg;                             // overlay after flash6

  proj_qkv<<<dim3(NPOS / 64, BB), 256, 0, stream>>>(x, Wtheta, Wphi, Wg, Qg, Kg, Vtg);
  flash6  <<<dim3(NPOS / 128, KSPL, BB), 256, 0, stream>>>(Qg, Kg, Vtg, Opart, Mpart, Lpart);
  merge_kernel<<<dim3(BB * NPOS / 512), 256, 0, stream>>>(Opart, Mpart, Lpart, Yt);
  zres_kernel<<<dim3(NPOS / 128, CCH / 128, BB), 256, 0, stream>>>(x, Wz, Yt, out);
}

// Round 2
// 415.542 us; speedup vs baseline: 1.0721x; 1.0721x over previous
//
#include <hip/hip_runtime.h>
#include <cstdint>

// SpacetimeNonLocalBlock: B=4, C=256, T*H*W=N=6272, IC=128.
// R9: flash7 = flash6 with two mechanistic fixes from R8's counter post-mortem:
// (1) V LDS granule layout changed to pos(dr,c)=dr*4+(c^((dr>>1)&3)) — PV
//     ds_read_b128 now hits all 8 bank-quads per 8 lanes (R8's layout hit 4
//     of 8 -> 8-way conflict, SQ_LDS_BANK_CONFLICT 14.7M). Source-side
//     pre-swizzle only; LDS dest stays linear for global_load_lds.
// (2) XCD-slab swizzle: flat 784-block grid decoded so XCD k (=flat%8) hosts
//     K/V slabs {2k,2k+1} only (1.6 MB/L2, 49 sharers co-located). R8 spread
//     each slab over 8 L2s -> FETCH 125 MB (2x flash5).
// Occupancy win of R8 kept: no stg regs, 64 VGPR + 64 AGPR = 4 waves/SIMD.

#define BB   4
#define CCH  256
#define NPOS 6272
#define ICH  128
#define BNIC ((size_t)BB * NPOS * ICH)
#define KSPL 4
#define KLEN (NPOS / KSPL)   // 1568
#define TKF  32
#define NITK (KLEN / TKF)    // 49
#define SLACK 12.0f

typedef __attribute__((ext_vector_type(8)))  _Float16 h8v;  // 8 f16 MFMA frag
typedef __attribute__((ext_vector_type(16))) float fx16;    // 32x32 acc

__device__ __forceinline__ unsigned short f2h(float f) {
  _Float16 h = (_Float16)f;
  return __builtin_bit_cast(unsigned short, h);
}
__device__ __forceinline__ unsigned int pkh(float lo, float hi) {
  return __builtin_bit_cast(unsigned int, __builtin_amdgcn_cvt_pkrtz(lo, hi));
}

// ---------------------------------------------------------------------------
// proj_qkv: fused Q/K/V projections. grid (N/64, B); block 256.
// Q,K -> [b][n][128] f16 (Q pre-scaled log2e); V -> V^T [b][128][N] f16.
// LDS 30.5 KB: Xt[16][68] + Wt[6][16][68]. Inner: 1 av + 6 bv b128 per kk.
// ---------------------------------------------------------------------------
__global__ __launch_bounds__(256, 1)
void proj_qkv(const float* __restrict__ x,
              const float* __restrict__ Wtheta,
              const float* __restrict__ Wphi,
              const float* __restrict__ Wg,
              unsigned short* __restrict__ Qg,
              unsigned short* __restrict__ Kg,
              unsigned short* __restrict__ Vtg) {
  const int n0 = blockIdx.x * 64;
  const int b  = blockIdx.y;
  __shared__ float Xt[16][68];      // [k][n]
  __shared__ float Wt[6][16][68];   // [tile][k][o]
  const int tid = threadIdx.x;
  const int tx = tid & 15, ty = tid >> 4;
  float acc[6][4][4] = {};          // [tile][n_i][o_j]
  const float* Ws[3] = {Wtheta, Wphi, Wg};

  for (int c0 = 0; c0 < CCH; c0 += 16) {
    {
      const int nn = tid & 63, k4 = tid >> 6;
      #pragma unroll
      for (int q = 0; q < 4; ++q) {
        const int kk = k4 + q * 4;
        Xt[kk][nn] = x[((size_t)(b * CCH + c0 + kk)) * NPOS + n0 + nn];
      }
      const int wk = tid & 15, wo = tid >> 4;
      #pragma unroll
      for (int w = 0; w < 6; ++w) {
        const float* W = Ws[w >> 1];
        const int o_half = (w & 1) * 64;
        #pragma unroll
        for (int q = 0; q < 4; ++q) {
          const int oo = wo + q * 16;
          Wt[w][wk][oo] = W[(size_t)(o_half + oo) * CCH + c0 + wk];
        }
      }
    }
    __syncthreads();
    #pragma unroll
    for (int kk = 0; kk < 16; ++kk) {
      const float4 av = *(const float4*)&Xt[kk][ty * 4];
      const float a_[4] = {av.x, av.y, av.z, av.w};
      #pragma unroll
      for (int w = 0; w < 6; ++w) {
        const float4 bv = *(const float4*)&Wt[w][kk][tx * 4];
        const float b_[4] = {bv.x, bv.y, bv.z, bv.w};
        #pragma unroll
        for (int i = 0; i < 4; ++i)
          #pragma unroll
          for (int j = 0; j < 4; ++j) acc[w][i][j] += a_[i] * b_[j];
      }
    }
    __syncthreads();
  }

  const float LOG2E = 1.4426950408889634f;
  // Q (tiles 0,1) and K (tiles 2,3): [n][o] rows
  #pragma unroll
  for (int w = 0; w < 4; ++w) {
    const int o_half = (w & 1) * 64;
    unsigned short* Out = (w < 2) ? Qg : Kg;
    const float scl = (w < 2) ? LOG2E : 1.0f;
    #pragma unroll
    for (int i = 0; i < 4; ++i) {
      ushort4 v;
      v.x = f2h(acc[w][i][0] * scl); v.y = f2h(acc[w][i][1] * scl);
      v.z = f2h(acc[w][i][2] * scl); v.w = f2h(acc[w][i][3] * scl);
      *(ushort4*)&Out[((size_t)b * NPOS + n0 + ty * 4 + i) * ICH + o_half + tx * 4] = v;
    }
  }
  // V (tiles 4,5): V^T[o][n] — transpose in-register (i<->j roles)
  #pragma unroll
  for (int w = 4; w < 6; ++w) {
    const int o_half = (w & 1) * 64;
    #pragma unroll
    for (int j = 0; j < 4; ++j) {
      const int o = o_half + tx * 4 + j;
      ushort4 v;
      v.x = f2h(acc[w][0][j]); v.y = f2h(acc[w][1][j]);
      v.z = f2h(acc[w][2][j]); v.w = f2h(acc[w][3][j]);
      *(ushort4*)&Vtg[((size_t)b * ICH + o) * NPOS + n0 + ty * 4] = v;
    }
  }
}

// ---------------------------------------------------------------------------
// flash7: flat grid 784 = 8 XCD * 2 slabs * 49 n-tiles. 4 waves, q=32/wave,
// TK=32, slack-fold softmax. LDS 32 KB: Ks[2][32x128] 16-slot xor-swz,
// Vs[2][128x32] granule layout dr*4+(c^((dr>>1)&3)). Staging: global_load_lds
// w=16, per-lane pre-swizzled source, linear LDS dest.
// ---------------------------------------------------------------------------
__global__ __launch_bounds__(256, 4)
void flash7(const unsigned short* __restrict__ Qg,
            const unsigned short* __restrict__ Kg,
            const unsigned short* __restrict__ Vtg,
            unsigned short* __restrict__ Opart,
            float* __restrict__ Mpart,
            float* __restrict__ Lpart) {
  __shared__ unsigned short Ks[2][TKF * 128];   // 8 KB per buf
  __shared__ unsigned short Vs[2][128 * 32];    // 8 KB per buf

  // XCD-slab swizzle: flat id f -> xcd = f&7 hosts slabs {2*xcd, 2*xcd+1}.
  const int f   = blockIdx.x;
  const int xcd = f & 7, j = f >> 3;            // j in [0,98)
  const int hi  = (j >= NITK) ? 1 : 0;
  const int slab = xcd * 2 + hi;                // [0,16)
  const int itile = j - hi * NITK;              // [0,49)
  const int b   = slab >> 2;
  const int spl = slab & 3;
  const int n0  = itile * 128;
  const int kb  = spl * KLEN;

  const int tid = threadIdx.x;
  const int lane = tid & 63, wv = tid >> 6;
  const int qlane = lane & 31, g = lane >> 5;
  const int swz = qlane & 15;

  h8v qf[8];
  {
    const size_t qbase = ((size_t)b * NPOS + n0 + 32 * wv + qlane) * ICH;
    #pragma unroll
    for (int cs = 0; cs < 8; ++cs)
      qf[cs] = *(const h8v*)&Qg[qbase + cs * 16 + g * 8];
  }

  // Per-lane 32-bit source offsets for global_load_lds staging.
  // Wave wv, inst i covers LDS ushorts [(wv*2+i)*512, +512); the source is
  // pre-permuted so the linear LDS image carries the swizzled layout.
  unsigned kOff[2], vOff[2];
  #pragma unroll
  for (int i = 0; i < 2; ++i) {
    const unsigned uoff = (unsigned)(wv * 2 + i) * 512 + (unsigned)lane * 8;
    // K: row-major [32][128], 16B slot s at column (s ^ (row&15)).
    const unsigned krow = uoff >> 7, kslot = (uoff >> 3) & 15;
    const unsigned kgc  = kslot ^ (krow & 15);
    kOff[i] = (unsigned)(b * NPOS + kb + krow) * ICH + kgc * 8;
    // V: granule position p = dr*4 + (c ^ ((dr>>1)&3))  ->  dr = p>>2,
    // c = (p&3) ^ ((p>>3)&3).  p = uoff>>3.
    const unsigned vrow = uoff >> 5;
    const unsigned vgc  = ((uoff >> 3) & 3) ^ ((uoff >> 6) & 3);
    vOff[i] = (unsigned)(b * ICH + vrow) * NPOS + kb + vgc * 8;
  }

  auto STAGE = [&](int bufi) {
    #pragma unroll
    for (int i = 0; i < 2; ++i) {
      __builtin_amdgcn_global_load_lds(
          (const __attribute__((address_space(1))) void*)&Kg[kOff[i]],
          (__attribute__((address_space(3))) void*)&Ks[bufi][(wv * 2 + i) * 512],
          16, 0, 0);
      __builtin_amdgcn_global_load_lds(
          (const __attribute__((address_space(1))) void*)&Vtg[vOff[i]],
          (__attribute__((address_space(3))) void*)&Vs[bufi][(wv * 2 + i) * 512],
          16, 0, 0);
      kOff[i] += TKF * ICH;
      vOff[i] += TKF;
    }
  };

  STAGE(0);
  __syncthreads();

  float m_run = -1e30f, m_true = -1e30f, l_run = 0.0f;
  fx16 accO[4];
  #pragma unroll
  for (int mt = 0; mt < 4; ++mt) accO[mt] = (fx16)(0.0f);

  for (int it = 0; it < NITK; ++it) {
    const int cur = it & 1;
    if (it + 1 < NITK) STAGE(cur ^ 1);   // prefetch overlaps this tile's compute

    // ---- S^T = K . Q^T ----
    fx16 accS = (fx16)(0.0f);
    #pragma unroll
    for (int cs = 0; cs < 8; ++cs) {
      const h8v aK = *(const h8v*)&Ks[cur][qlane * 128 + ((2 * cs + g) ^ swz) * 8];
      accS = __builtin_amdgcn_mfma_f32_32x32x16_f16(aK, qf[cs], accS, 0, 0, 0);
    }

    // ---- slack-fold online softmax (log2 domain), tree max ----
    float a0 = fmaxf(accS[0], accS[1]),   a1 = fmaxf(accS[2], accS[3]);
    float a2 = fmaxf(accS[4], accS[5]),   a3 = fmaxf(accS[6], accS[7]);
    float a4 = fmaxf(accS[8], accS[9]),   a5 = fmaxf(accS[10], accS[11]);
    float a6 = fmaxf(accS[12], accS[13]), a7 = fmaxf(accS[14], accS[15]);
    a0 = fmaxf(a0, a1); a2 = fmaxf(a2, a3); a4 = fmaxf(a4, a5); a6 = fmaxf(a6, a7);
    float mx = fmaxf(fmaxf(a0, a2), fmaxf(a4, a6));
    mx = fmaxf(mx, __shfl_xor(mx, 32));
    m_true = fmaxf(m_true, mx);
    const bool fold = __any(mx > m_run + SLACK);
    const float mn = fold ? fmaxf(m_run, mx) : m_run;
    float lsum = 0.0f;
    unsigned int pk[4][2];
    #pragma unroll
    for (int u = 0; u < 4; ++u) {
      const float p0 = exp2f(accS[4 * u + 0] - mn);
      const float p1 = exp2f(accS[4 * u + 1] - mn);
      const float p2 = exp2f(accS[4 * u + 2] - mn);
      const float p3 = exp2f(accS[4 * u + 3] - mn);
      lsum += (p0 + p1) + (p2 + p3);
      pk[u][0] = pkh(p0, p1);
      pk[u][1] = pkh(p2, p3);
    }
    lsum += __shfl_xor(lsum, 32);
    if (fold) {
      const float alpha = exp2f(m_run - mn);
      l_run = l_run * alpha + lsum;
      m_run = mn;
      #pragma unroll
      for (int mt = 0; mt < 4; ++mt)
        #pragma unroll
        for (int r = 0; r < 16; ++r) accO[mt][r] *= alpha;
    } else {
      l_run += lsum;
    }

    // ---- PV: O^T += V^T . P^T ----
    #pragma unroll
    for (int s = 0; s < 2; ++s) {
      const unsigned int s0 = pk[2 * s + (g ^ 1)][0];
      const unsigned int s1 = pk[2 * s + (g ^ 1)][1];
      const unsigned int t0 = __shfl_xor(s0, 32);
      const unsigned int t1 = __shfl_xor(s1, 32);
      union { unsigned int u[4]; h8v v; } bP;
      bP.u[0] = g ? t0 : pk[2 * s][0];
      bP.u[1] = g ? t1 : pk[2 * s][1];
      bP.u[2] = g ? pk[2 * s + 1][0] : t0;
      bP.u[3] = g ? pk[2 * s + 1][1] : t1;
      // V granule (dr = 32mt+qlane, c = 2s+g) at ushort index
      // dr*32 + ((c ^ ((qlane>>1)&3)))*8   (16mt & 3 == 0)
      const int vbase = qlane * 32 + (((2 * s + g) ^ ((qlane >> 1) & 3)) * 8);
      #pragma unroll
      for (int mt = 0; mt < 4; ++mt) {
        const h8v aV = *(const h8v*)&Vs[cur][mt * 1024 + vbase];
        accO[mt] = __builtin_amdgcn_mfma_f32_32x32x16_f16(aV, bP.v, accO[mt], 0, 0, 0);
      }
    }

    __syncthreads();   // drains prefetch (vmcnt) + finishes reads of cur
  }

  // epilogue: renormalize to true max, store f16 partial O + (m,l)
  const float scale = exp2f(m_run - m_true);
  const int ncol = n0 + 32 * wv + qlane;
  const size_t obase = (size_t)(b * KSPL + spl) * ICH * NPOS;
  #pragma unroll
  for (int mt = 0; mt < 4; ++mt)
    #pragma unroll
    for (int r = 0; r < 16; ++r) {
      const int d = 32 * mt + (r & 3) + 8 * (r >> 2) + 4 * g;
      Opart[obase + (size_t)d * NPOS + ncol] = f2h(accO[mt][r] * scale);
    }
  if (g == 0) {
    Mpart[(size_t)(b * KSPL + spl) * NPOS + ncol] = m_true;
    Lpart[(size_t)(b * KSPL + spl) * NPOS + ncol] = l_run * scale;
  }
}

// ---------------------------------------------------------------------------
// merge (2n per thread): Y^T[b][d][n] = sum_s 2^{m_s-M} O_s / sum_s 2^{m_s-M} l_s
// ---------------------------------------------------------------------------
__global__ __launch_bounds__(256, 2)
void merge_kernel(const unsigned short* __restrict__ Opart,
                  const float* __restrict__ Mpart,
                  const float* __restrict__ Lpart,
                  float* __restrict__ Yt) {
  const int idx = (blockIdx.x * 256 + threadIdx.x) * 2;   // 0 .. B*N-1 step 2
  const int b = idx / NPOS, n = idx % NPOS;
  float m[KSPL][2], l[KSPL][2], M0 = -1e30f, M1 = -1e30f;
  #pragma unroll
  for (int s = 0; s < KSPL; ++s) {
    const size_t base = (size_t)(b * KSPL + s) * NPOS + n;
    m[s][0] = Mpart[base]; m[s][1] = Mpart[base + 1];
    l[s][0] = Lpart[base]; l[s][1] = Lpart[base + 1];
    M0 = fmaxf(M0, m[s][0]); M1 = fmaxf(M1, m[s][1]);
  }
  float w[KSPL][2], lt0 = 0.0f, lt1 = 0.0f;
  #pragma unroll
  for (int s = 0; s < KSPL; ++s) {
    w[s][0] = exp2f(m[s][0] - M0); lt0 += w[s][0] * l[s][0];
    w[s][1] = exp2f(m[s][1] - M1); lt1 += w[s][1] * l[s][1];
  }
  const float inv0 = 1.0f / lt0, inv1 = 1.0f / lt1;
  for (int d = 0; d < ICH; ++d) {
    float a0 = 0.0f, a1 = 0.0f;
    #pragma unroll
    for (int s = 0; s < KSPL; ++s) {
      const unsigned int u = *(const unsigned int*)
        &Opart[((size_t)(b * KSPL + s) * ICH + d) * NPOS + n];
      a0 += w[s][0] * (float)__builtin_bit_cast(_Float16, (unsigned short)(u & 0xffff));
      a1 += w[s][1] * (float)__builtin_bit_cast(_Float16, (unsigned short)(u >> 16));
    }
    float2 o; o.x = a0 * inv0; o.y = a1 * inv1;
    *(float2*)&Yt[((size_t)b * ICH + d) * NPOS + n] = o;
  }
}

// ---------------------------------------------------------------------------
// zres: out[b][c][n] = sum_ic Wz[c][ic]*Y^T[b][ic][n] + x. 128x128 block,
// 8x8 thread tile via wave quadrants (both LDS operand reads <=2-way).
// ---------------------------------------------------------------------------
__global__ __launch_bounds__(256, 2)
void zres_kernel(const float* __restrict__ x,
                 const float* __restrict__ Wz,
                 const float* __restrict__ Yt,
                 float* __restrict__ out) {
  const int n0 = blockIdx.x * 128;
  const int c0 = blockIdx.y * 128;
  const int b  = blockIdx.z;
  __shared__ float Yts[16][128];   // [k(ic)][n]
  __shared__ float Wzt[16][128];   // [k][c]
  const int tid = threadIdx.x;
  const int lane = tid & 63, wv = tid >> 6;
  const int tn = lane & 7, tc = lane >> 3;           // 8x8 within wave
  const int nb = (wv & 1) * 64 + tn * 8;             // n offset in block
  const int cb = (wv >> 1) * 64 + tc * 8;            // c offset in block
  float acc[8][8] = {};                              // [c_i][n_j]

  for (int ic0 = 0; ic0 < ICH; ic0 += 16) {
    {
      const int nn = tid & 127, kh = tid >> 7;
      #pragma unroll
      for (int q = 0; q < 8; ++q) {
        const int kk = kh + q * 2;
        Yts[kk][nn] = Yt[((size_t)b * ICH + ic0 + kk) * NPOS + n0 + nn];
      }
      const int wk = tid & 15, wo = tid >> 4;
      #pragma unroll
      for (int q = 0; q < 8; ++q) {
        const int cc = wo + q * 16;
        Wzt[wk][cc] = Wz[(size_t)(c0 + cc) * ICH + ic0 + wk];
      }
    }
    __syncthreads();
    #pragma unroll
    for (int kk = 0; kk < 16; ++kk) {
      const float4 a0 = *(const float4*)&Wzt[kk][cb];
      const float4 a1 = *(const float4*)&Wzt[kk][cb + 4];
      const float4 b0 = *(const float4*)&Yts[kk][nb];
      const float4 b1 = *(const float4*)&Yts[kk][nb + 4];
      const float a_[8] = {a0.x, a0.y, a0.z, a0.w, a1.x, a1.y, a1.z, a1.w};
      const float b_[8] = {b0.x, b0.y, b0.z, b0.w, b1.x, b1.y, b1.z, b1.w};
      #pragma unroll
      for (int i = 0; i < 8; ++i)
        #pragma unroll
        for (int j = 0; j < 8; ++j) acc[i][j] += a_[i] * b_[j];
    }
    __syncthreads();
  }
  #pragma unroll
  for (int i = 0; i < 8; ++i) {
    const size_t base = ((size_t)(b * CCH + c0 + cb + i)) * NPOS + n0 + nb;
    const float4 x0 = *(const float4*)&x[base];
    const float4 x1 = *(const float4*)&x[base + 4];
    float4 v0, v1;
    v0.x = acc[i][0] + x0.x; v0.y = acc[i][1] + x0.y;
    v0.z = acc[i][2] + x0.z; v0.w = acc[i][3] + x0.w;
    v1.x = acc[i][4] + x1.x; v1.y = acc[i][5] + x1.y;
    v1.z = acc[i][6] + x1.z; v1.w = acc[i][7] + x1.w;
    *(float4*)&out[base]     = v0;
    *(float4*)&out[base + 4] = v1;
  }
}

// ---------------------------------------------------------------------------
extern "C" void kernel_launch(void* const* d_in, const int* in_sizes, int n_in,
                              void* d_out, int out_size, void* d_ws, size_t ws_size,
                              hipStream_t stream) {
  const float* x      = (const float*)d_in[0];
  const float* Wg     = (const float*)d_in[1];
  const float* Wtheta = (const float*)d_in[2];
  const float* Wphi   = (const float*)d_in[3];
  const float* Wz     = (const float*)d_in[4];
  float* out = (float*)d_out;

  unsigned short* Qg    = (unsigned short*)d_ws;
  unsigned short* Kg    = Qg + BNIC;
  unsigned short* Vtg   = Kg + BNIC;
  unsigned short* Opart = Vtg + BNIC;                    // KSPL*BNIC ushorts
  float* Mpart = (float*)(Opart + (size_t)KSPL * BNIC);  // KSPL*B*N floats
  float* Lpart = Mpart + (size_t)KSPL * BB * NPOS;       // KSPL*B*N floats
  float* Yt    = (float*)Qg;                             // overlay after flash7

  proj_qkv<<<dim3(NPOS / 64, BB), 256, 0, stream>>>(x, Wtheta, Wphi, Wg, Qg, Kg, Vtg);
  flash7  <<<dim3(BB * KSPL * NITK), 256, 0, stream>>>(Qg, Kg, Vtg, Opart, Mpart, Lpart);
  merge_kernel<<<dim3(BB * NPOS / 512), 256, 0, stream>>>(Opart, Mpart, Lpart, Yt);
  zres_kernel<<<dim3(NPOS / 128, CCH / 128, BB), 256, 0, stream>>>(x, Wz, Yt, out);
}

// Round 3
// 410.301 us; speedup vs baseline: 1.0858x; 1.0128x over previous
//
#include <hip/hip_runtime.h>
#include <cstdint>

// SpacetimeNonLocalBlock: B=4, C=256, T*H*W=N=6272, IC=128.
// R10: flash8 = flash7 with the sync structure rebuilt as a depth-2 counted-
// vmcnt pipeline (T3/T4). R7-R9 all issued prefetch at iter top and then hit
// __syncthreads() at iter bottom, whose implicit s_waitcnt vmcnt(0) drained
// the just-issued loads every iteration (~11k cyc/iter for ~500 cyc work).
// Now: 3 LDS buffers; per iter: s_waitcnt vmcnt(4) -> raw s_barrier ->
// STAGE(tile it+2) -> compute(buf it%3). Loads issued 2 iters before use;
// vmcnt never drains to 0 in-loop. T5 setprio(1) wraps MFMA clusters.
// Kept from R9: XCD-slab swizzle (FETCH 25MB), conflict-free K 16-slot xor +
// V granule dr*4+(c^((dr>>1)&3)) layouts via pre-swizzled gload_lds sources.

#define BB   4
#define CCH  256
#define NPOS 6272
#define ICH  128
#define BNIC ((size_t)BB * NPOS * ICH)
#define KSPL 4
#define KLEN (NPOS / KSPL)   // 1568
#define TKF  32
#define NITK (KLEN / TKF)    // 49
#define SLACK 12.0f

typedef __attribute__((ext_vector_type(8)))  _Float16 h8v;  // 8 f16 MFMA frag
typedef __attribute__((ext_vector_type(16))) float fx16;    // 32x32 acc

__device__ __forceinline__ unsigned short f2h(float f) {
  _Float16 h = (_Float16)f;
  return __builtin_bit_cast(unsigned short, h);
}
__device__ __forceinline__ unsigned int pkh(float lo, float hi) {
  return __builtin_bit_cast(unsigned int, __builtin_amdgcn_cvt_pkrtz(lo, hi));
}

// ---------------------------------------------------------------------------
// proj_qkv: fused Q/K/V projections. grid (N/64, B); block 256.
// Q,K -> [b][n][128] f16 (Q pre-scaled log2e); V -> V^T [b][128][N] f16.
// LDS 30.5 KB: Xt[16][68] + Wt[6][16][68]. Inner: 1 av + 6 bv b128 per kk.
// ---------------------------------------------------------------------------
__global__ __launch_bounds__(256, 1)
void proj_qkv(const float* __restrict__ x,
              const float* __restrict__ Wtheta,
              const float* __restrict__ Wphi,
              const float* __restrict__ Wg,
              unsigned short* __restrict__ Qg,
              unsigned short* __restrict__ Kg,
              unsigned short* __restrict__ Vtg) {
  const int n0 = blockIdx.x * 64;
  const int b  = blockIdx.y;
  __shared__ float Xt[16][68];      // [k][n]
  __shared__ float Wt[6][16][68];   // [tile][k][o]
  const int tid = threadIdx.x;
  const int tx = tid & 15, ty = tid >> 4;
  float acc[6][4][4] = {};          // [tile][n_i][o_j]
  const float* Ws[3] = {Wtheta, Wphi, Wg};

  for (int c0 = 0; c0 < CCH; c0 += 16) {
    {
      const int nn = tid & 63, k4 = tid >> 6;
      #pragma unroll
      for (int q = 0; q < 4; ++q) {
        const int kk = k4 + q * 4;
        Xt[kk][nn] = x[((size_t)(b * CCH + c0 + kk)) * NPOS + n0 + nn];
      }
      const int wk = tid & 15, wo = tid >> 4;
      #pragma unroll
      for (int w = 0; w < 6; ++w) {
        const float* W = Ws[w >> 1];
        const int o_half = (w & 1) * 64;
        #pragma unroll
        for (int q = 0; q < 4; ++q) {
          const int oo = wo + q * 16;
          Wt[w][wk][oo] = W[(size_t)(o_half + oo) * CCH + c0 + wk];
        }
      }
    }
    __syncthreads();
    #pragma unroll
    for (int kk = 0; kk < 16; ++kk) {
      const float4 av = *(const float4*)&Xt[kk][ty * 4];
      const float a_[4] = {av.x, av.y, av.z, av.w};
      #pragma unroll
      for (int w = 0; w < 6; ++w) {
        const float4 bv = *(const float4*)&Wt[w][kk][tx * 4];
        const float b_[4] = {bv.x, bv.y, bv.z, bv.w};
        #pragma unroll
        for (int i = 0; i < 4; ++i)
          #pragma unroll
          for (int j = 0; j < 4; ++j) acc[w][i][j] += a_[i] * b_[j];
      }
    }
    __syncthreads();
  }

  const float LOG2E = 1.4426950408889634f;
  // Q (tiles 0,1) and K (tiles 2,3): [n][o] rows
  #pragma unroll
  for (int w = 0; w < 4; ++w) {
    const int o_half = (w & 1) * 64;
    unsigned short* Out = (w < 2) ? Qg : Kg;
    const float scl = (w < 2) ? LOG2E : 1.0f;
    #pragma unroll
    for (int i = 0; i < 4; ++i) {
      ushort4 v;
      v.x = f2h(acc[w][i][0] * scl); v.y = f2h(acc[w][i][1] * scl);
      v.z = f2h(acc[w][i][2] * scl); v.w = f2h(acc[w][i][3] * scl);
      *(ushort4*)&Out[((size_t)b * NPOS + n0 + ty * 4 + i) * ICH + o_half + tx * 4] = v;
    }
  }
  // V (tiles 4,5): V^T[o][n] — transpose in-register (i<->j roles)
  #pragma unroll
  for (int w = 4; w < 6; ++w) {
    const int o_half = (w & 1) * 64;
    #pragma unroll
    for (int j = 0; j < 4; ++j) {
      const int o = o_half + tx * 4 + j;
      ushort4 v;
      v.x = f2h(acc[w][0][j]); v.y = f2h(acc[w][1][j]);
      v.z = f2h(acc[w][2][j]); v.w = f2h(acc[w][3][j]);
      *(ushort4*)&Vtg[((size_t)b * ICH + o) * NPOS + n0 + ty * 4] = v;
    }
  }
}

// ---------------------------------------------------------------------------
// flash8: flat grid 784 = 8 XCD * 2 slabs * 49 n-tiles. 4 waves, q=32/wave,
// TK=32, slack-fold softmax. LDS 48 KB: Ks[3][32x128] 16-slot xor-swz,
// Vs[3][128x32] granule layout dr*4+(c^((dr>>1)&3)). Depth-2 counted-vmcnt
// pipeline: wait vmcnt(4); s_barrier; STAGE(it+2); compute(it%3).
// ---------------------------------------------------------------------------
__global__ __launch_bounds__(256, 4)
void flash8(const unsigned short* __restrict__ Qg,
            const unsigned short* __restrict__ Kg,
            const unsigned short* __restrict__ Vtg,
            unsigned short* __restrict__ Opart,
            float* __restrict__ Mpart,
            float* __restrict__ Lpart) {
  __shared__ unsigned short Ks[3][TKF * 128];   // 8 KB per buf
  __shared__ unsigned short Vs[3][128 * 32];    // 8 KB per buf

  // XCD-slab swizzle: flat id f -> xcd = f&7 hosts slabs {2*xcd, 2*xcd+1}.
  const int f   = blockIdx.x;
  const int xcd = f & 7, j = f >> 3;            // j in [0,98)
  const int hi  = (j >= NITK) ? 1 : 0;
  const int slab = xcd * 2 + hi;                // [0,16)
  const int itile = j - hi * NITK;              // [0,49)
  const int b   = slab >> 2;
  const int spl = slab & 3;
  const int n0  = itile * 128;
  const int kb  = spl * KLEN;

  const int tid = threadIdx.x;
  const int lane = tid & 63, wv = tid >> 6;
  const int qlane = lane & 31, g = lane >> 5;
  const int swz = qlane & 15;

  h8v qf[8];
  {
    const size_t qbase = ((size_t)b * NPOS + n0 + 32 * wv + qlane) * ICH;
    #pragma unroll
    for (int cs = 0; cs < 8; ++cs)
      qf[cs] = *(const h8v*)&Qg[qbase + cs * 16 + g * 8];
  }

  // Per-lane 32-bit source offsets for global_load_lds staging.
  // Wave wv, inst i covers LDS ushorts [(wv*2+i)*512, +512); the source is
  // pre-permuted so the linear LDS image carries the swizzled layout.
  unsigned kOff[2], vOff[2];
  #pragma unroll
  for (int i = 0; i < 2; ++i) {
    const unsigned uoff = (unsigned)(wv * 2 + i) * 512 + (unsigned)lane * 8;
    // K: row-major [32][128], 16B slot s at column (s ^ (row&15)).
    const unsigned krow = uoff >> 7, kslot = (uoff >> 3) & 15;
    const unsigned kgc  = kslot ^ (krow & 15);
    kOff[i] = (unsigned)(b * NPOS + kb + krow) * ICH + kgc * 8;
    // V: granule position p = dr*4 + (c ^ ((dr>>1)&3))  ->  dr = p>>2,
    // c = (p&3) ^ ((p>>3)&3).  p = uoff>>3.
    const unsigned vrow = uoff >> 5;
    const unsigned vgc  = ((uoff >> 3) & 3) ^ ((uoff >> 6) & 3);
    vOff[i] = (unsigned)(b * ICH + vrow) * NPOS + kb + vgc * 8;
  }

  // Each call stages the NEXT sequential k-tile into buffer bufi.
  auto STAGE = [&](int bufi) {
    #pragma unroll
    for (int i = 0; i < 2; ++i) {
      __builtin_amdgcn_global_load_lds(
          (const __attribute__((address_space(1))) void*)&Kg[kOff[i]],
          (__attribute__((address_space(3))) void*)&Ks[bufi][(wv * 2 + i) * 512],
          16, 0, 0);
      __builtin_amdgcn_global_load_lds(
          (const __attribute__((address_space(1))) void*)&Vtg[vOff[i]],
          (__attribute__((address_space(3))) void*)&Vs[bufi][(wv * 2 + i) * 512],
          16, 0, 0);
      kOff[i] += TKF * ICH;
      vOff[i] += TKF;
    }
  };

  STAGE(0);   // tile 0
  STAGE(1);   // tile 1  (8 loads in flight)

  float m_run = -1e30f, m_true = -1e30f, l_run = 0.0f;
  fx16 accO[4];
  #pragma unroll
  for (int mt = 0; mt < 4; ++mt) accO[mt] = (fx16)(0.0f);

  int cur = 0;
  for (int it = 0; it < NITK; ++it) {
    // Wait for tile `it`'s 4 loads (issued 2 iters ago); keep newer in flight.
    if (it < NITK - 1) {
      asm volatile("s_waitcnt vmcnt(4)" ::: "memory");
    } else {
      asm volatile("s_waitcnt vmcnt(0)" ::: "memory");
    }
    __builtin_amdgcn_s_barrier();   // all waves staged cur; all done reading
    __builtin_amdgcn_sched_barrier(0);
    if (it + 2 < NITK) STAGE(cur == 0 ? 2 : cur - 1);   // (cur+2)%3

    // ---- S^T = K . Q^T ----
    fx16 accS = (fx16)(0.0f);
    __builtin_amdgcn_s_setprio(1);
    #pragma unroll
    for (int cs = 0; cs < 8; ++cs) {
      const h8v aK = *(const h8v*)&Ks[cur][qlane * 128 + ((2 * cs + g) ^ swz) * 8];
      accS = __builtin_amdgcn_mfma_f32_32x32x16_f16(aK, qf[cs], accS, 0, 0, 0);
    }
    __builtin_amdgcn_s_setprio(0);

    // ---- slack-fold online softmax (log2 domain), tree max ----
    float a0 = fmaxf(accS[0], accS[1]),   a1 = fmaxf(accS[2], accS[3]);
    float a2 = fmaxf(accS[4], accS[5]),   a3 = fmaxf(accS[6], accS[7]);
    float a4 = fmaxf(accS[8], accS[9]),   a5 = fmaxf(accS[10], accS[11]);
    float a6 = fmaxf(accS[12], accS[13]), a7 = fmaxf(accS[14], accS[15]);
    a0 = fmaxf(a0, a1); a2 = fmaxf(a2, a3); a4 = fmaxf(a4, a5); a6 = fmaxf(a6, a7);
    float mx = fmaxf(fmaxf(a0, a2), fmaxf(a4, a6));
    mx = fmaxf(mx, __shfl_xor(mx, 32));
    m_true = fmaxf(m_true, mx);
    const bool fold = __any(mx > m_run + SLACK);
    const float mn = fold ? fmaxf(m_run, mx) : m_run;
    float lsum = 0.0f;
    unsigned int pk[4][2];
    #pragma unroll
    for (int u = 0; u < 4; ++u) {
      const float p0 = exp2f(accS[4 * u + 0] - mn);
      const float p1 = exp2f(accS[4 * u + 1] - mn);
      const float p2 = exp2f(accS[4 * u + 2] - mn);
      const float p3 = exp2f(accS[4 * u + 3] - mn);
      lsum += (p0 + p1) + (p2 + p3);
      pk[u][0] = pkh(p0, p1);
      pk[u][1] = pkh(p2, p3);
    }
    lsum += __shfl_xor(lsum, 32);
    if (fold) {
      const float alpha = exp2f(m_run - mn);
      l_run = l_run * alpha + lsum;
      m_run = mn;
      #pragma unroll
      for (int mt = 0; mt < 4; ++mt)
        #pragma unroll
        for (int r = 0; r < 16; ++r) accO[mt][r] *= alpha;
    } else {
      l_run += lsum;
    }

    // ---- PV: O^T += V^T . P^T ----
    #pragma unroll
    for (int s = 0; s < 2; ++s) {
      const unsigned int s0 = pk[2 * s + (g ^ 1)][0];
      const unsigned int s1 = pk[2 * s + (g ^ 1)][1];
      const unsigned int t0 = __shfl_xor(s0, 32);
      const unsigned int t1 = __shfl_xor(s1, 32);
      union { unsigned int u[4]; h8v v; } bP;
      bP.u[0] = g ? t0 : pk[2 * s][0];
      bP.u[1] = g ? t1 : pk[2 * s][1];
      bP.u[2] = g ? pk[2 * s + 1][0] : t0;
      bP.u[3] = g ? pk[2 * s + 1][1] : t1;
      // V granule (dr = 32mt+qlane, c = 2s+g) at ushort index
      // dr*32 + ((c ^ ((qlane>>1)&3)))*8   (16mt & 3 == 0)
      const int vbase = qlane * 32 + (((2 * s + g) ^ ((qlane >> 1) & 3)) * 8);
      __builtin_amdgcn_s_setprio(1);
      #pragma unroll
      for (int mt = 0; mt < 4; ++mt) {
        const h8v aV = *(const h8v*)&Vs[cur][mt * 1024 + vbase];
        accO[mt] = __builtin_amdgcn_mfma_f32_32x32x16_f16(aV, bP.v, accO[mt], 0, 0, 0);
      }
      __builtin_amdgcn_s_setprio(0);
    }

    cur = (cur == 2) ? 0 : cur + 1;
  }

  // epilogue: renormalize to true max, store f16 partial O + (m,l)
  const float scale = exp2f(m_run - m_true);
  const int ncol = n0 + 32 * wv + qlane;
  const size_t obase = (size_t)(b * KSPL + spl) * ICH * NPOS;
  #pragma unroll
  for (int mt = 0; mt < 4; ++mt)
    #pragma unroll
    for (int r = 0; r < 16; ++r) {
      const int d = 32 * mt + (r & 3) + 8 * (r >> 2) + 4 * g;
      Opart[obase + (size_t)d * NPOS + ncol] = f2h(accO[mt][r] * scale);
    }
  if (g == 0) {
    Mpart[(size_t)(b * KSPL + spl) * NPOS + ncol] = m_true;
    Lpart[(size_t)(b * KSPL + spl) * NPOS + ncol] = l_run * scale;
  }
}

// ---------------------------------------------------------------------------
// merge (2n per thread): Y^T[b][d][n] = sum_s 2^{m_s-M} O_s / sum_s 2^{m_s-M} l_s
// ---------------------------------------------------------------------------
__global__ __launch_bounds__(256, 2)
void merge_kernel(const unsigned short* __restrict__ Opart,
                  const float* __restrict__ Mpart,
                  const float* __restrict__ Lpart,
                  float* __restrict__ Yt) {
  const int idx = (blockIdx.x * 256 + threadIdx.x) * 2;   // 0 .. B*N-1 step 2
  const int b = idx / NPOS, n = idx % NPOS;
  float m[KSPL][2], l[KSPL][2], M0 = -1e30f, M1 = -1e30f;
  #pragma unroll
  for (int s = 0; s < KSPL; ++s) {
    const size_t base = (size_t)(b * KSPL + s) * NPOS + n;
    m[s][0] = Mpart[base]; m[s][1] = Mpart[base + 1];
    l[s][0] = Lpart[base]; l[s][1] = Lpart[base + 1];
    M0 = fmaxf(M0, m[s][0]); M1 = fmaxf(M1, m[s][1]);
  }
  float w[KSPL][2], lt0 = 0.0f, lt1 = 0.0f;
  #pragma unroll
  for (int s = 0; s < KSPL; ++s) {
    w[s][0] = exp2f(m[s][0] - M0); lt0 += w[s][0] * l[s][0];
    w[s][1] = exp2f(m[s][1] - M1); lt1 += w[s][1] * l[s][1];
  }
  const float inv0 = 1.0f / lt0, inv1 = 1.0f / lt1;
  for (int d = 0; d < ICH; ++d) {
    float a0 = 0.0f, a1 = 0.0f;
    #pragma unroll
    for (int s = 0; s < KSPL; ++s) {
      const unsigned int u = *(const unsigned int*)
        &Opart[((size_t)(b * KSPL + s) * ICH + d) * NPOS + n];
      a0 += w[s][0] * (float)__builtin_bit_cast(_Float16, (unsigned short)(u & 0xffff));
      a1 += w[s][1] * (float)__builtin_bit_cast(_Float16, (unsigned short)(u >> 16));
    }
    float2 o; o.x = a0 * inv0; o.y = a1 * inv1;
    *(float2*)&Yt[((size_t)b * ICH + d) * NPOS + n] = o;
  }
}

// ---------------------------------------------------------------------------
// zres: out[b][c][n] = sum_ic Wz[c][ic]*Y^T[b][ic][n] + x. 128x128 block,
// 8x8 thread tile via wave quadrants (both LDS operand reads <=2-way).
// ---------------------------------------------------------------------------
__global__ __launch_bounds__(256, 2)
void zres_kernel(const float* __restrict__ x,
                 const float* __restrict__ Wz,
                 const float* __restrict__ Yt,
                 float* __restrict__ out) {
  const int n0 = blockIdx.x * 128;
  const int c0 = blockIdx.y * 128;
  const int b  = blockIdx.z;
  __shared__ float Yts[16][128];   // [k(ic)][n]
  __shared__ float Wzt[16][128];   // [k][c]
  const int tid = threadIdx.x;
  const int lane = tid & 63, wv = tid >> 6;
  const int tn = lane & 7, tc = lane >> 3;           // 8x8 within wave
  const int nb = (wv & 1) * 64 + tn * 8;             // n offset in block
  const int cb = (wv >> 1) * 64 + tc * 8;            // c offset in block
  float acc[8][8] = {};                              // [c_i][n_j]

  for (int ic0 = 0; ic0 < ICH; ic0 += 16) {
    {
      const int nn = tid & 127, kh = tid >> 7;
      #pragma unroll
      for (int q = 0; q < 8; ++q) {
        const int kk = kh + q * 2;
        Yts[kk][nn] = Yt[((size_t)b * ICH + ic0 + kk) * NPOS + n0 + nn];
      }
      const int wk = tid & 15, wo = tid >> 4;
      #pragma unroll
      for (int q = 0; q < 8; ++q) {
        const int cc = wo + q * 16;
        Wzt[wk][cc] = Wz[(size_t)(c0 + cc) * ICH + ic0 + wk];
      }
    }
    __syncthreads();
    #pragma unroll
    for (int kk = 0; kk < 16; ++kk) {
      const float4 a0 = *(const float4*)&Wzt[kk][cb];
      const float4 a1 = *(const float4*)&Wzt[kk][cb + 4];
      const float4 b0 = *(const float4*)&Yts[kk][nb];
      const float4 b1 = *(const float4*)&Yts[kk][nb + 4];
      const float a_[8] = {a0.x, a0.y, a0.z, a0.w, a1.x, a1.y, a1.z, a1.w};
      const float b_[8] = {b0.x, b0.y, b0.z, b0.w, b1.x, b1.y, b1.z, b1.w};
      #pragma unroll
      for (int i = 0; i < 8; ++i)
        #pragma unroll
        for (int j = 0; j < 8; ++j) acc[i][j] += a_[i] * b_[j];
    }
    __syncthreads();
  }
  #pragma unroll
  for (int i = 0; i < 8; ++i) {
    const size_t base = ((size_t)(b * CCH + c0 + cb + i)) * NPOS + n0 + nb;
    const float4 x0 = *(const float4*)&x[base];
    const float4 x1 = *(const float4*)&x[base + 4];
    float4 v0, v1;
    v0.x = acc[i][0] + x0.x; v0.y = acc[i][1] + x0.y;
    v0.z = acc[i][2] + x0.z; v0.w = acc[i][3] + x0.w;
    v1.x = acc[i][4] + x1.x; v1.y = acc[i][5] + x1.y;
    v1.z = acc[i][6] + x1.z; v1.w = acc[i][7] + x1.w;
    *(float4*)&out[base]     = v0;
    *(float4*)&out[base + 4] = v1;
  }
}

// ---------------------------------------------------------------------------
extern "C" void kernel_launch(void* const* d_in, const int* in_sizes, int n_in,
                              void* d_out, int out_size, void* d_ws, size_t ws_size,
                              hipStream_t stream) {
  const float* x      = (const float*)d_in[0];
  const float* Wg     = (const float*)d_in[1];
  const float* Wtheta = (const float*)d_in[2];
  const float* Wphi   = (const float*)d_in[3];
  const float* Wz     = (const float*)d_in[4];
  float* out = (float*)d_out;

  unsigned short* Qg    = (unsigned short*)d_ws;
  unsigned short* Kg    = Qg + BNIC;
  unsigned short* Vtg   = Kg + BNIC;
  unsigned short* Opart = Vtg + BNIC;                    // KSPL*BNIC ushorts
  float* Mpart = (float*)(Opart + (size_t)KSPL * BNIC);  // KSPL*B*N floats
  float* Lpart = Mpart + (size_t)KSPL * BB * NPOS;       // KSPL*B*N floats
  float* Yt    = (float*)Qg;                             // overlay after flash8

  proj_qkv<<<dim3(NPOS / 64, BB), 256, 0, stream>>>(x, Wtheta, Wphi, Wg, Qg, Kg, Vtg);
  flash8  <<<dim3(BB * KSPL * NITK), 256, 0, stream>>>(Qg, Kg, Vtg, Opart, Mpart, Lpart);
  merge_kernel<<<dim3(BB * NPOS / 512), 256, 0, stream>>>(Opart, Mpart, Lpart, Yt);
  zres_kernel<<<dim3(NPOS / 128, CCH / 128, BB), 256, 0, stream>>>(x, Wz, Yt, out);
}